// Round 4
// baseline (405.647 us; speedup 1.0000x reference)
//
#include <hip/hip_runtime.h>
#include <hip/hip_bf16.h>

#define N_NODES 50000
#define N_EDGES 500000
#define HDIM 128
#define HEADS 3
#define BB 512
#define LL 10
#define NEG_SLOPE 0.2f

typedef __hip_bfloat16 bf16;
typedef __bf16 v8bf __attribute__((ext_vector_type(8)));
typedef float f32x4 __attribute__((ext_vector_type(4)));

// ---------------- utility ----------------

__global__ void k_zero1(int* a, int n){
  int i = blockIdx.x*256 + threadIdx.x;
  if(i < n) a[i] = 0;
}

__global__ void k_hist(const int* __restrict__ dst, int* __restrict__ cnt, int E){
  int e = blockIdx.x*256 + threadIdx.x;
  if(e < E) atomicAdd(&cnt[dst[e]], 1);
}

// single-block scan over counts -> offsets[0..N], offs[0]=0 (race-free barriers)
__global__ void k_scan(const int* __restrict__ cnt, int* __restrict__ offs, int N){
  __shared__ int tmp[1024];
  int tid = threadIdx.x;
  int running = 0;
  if(tid == 0) offs[0] = 0;
  for(int base = 0; base < N; base += 1024){
    int v = (base + tid < N) ? cnt[base + tid] : 0;
    __syncthreads();                 // protect prev-iter tmp[1023] reads
    tmp[tid] = v; __syncthreads();
    for(int s = 1; s < 1024; s <<= 1){
      int t = (tid >= s) ? tmp[tid - s] : 0;
      __syncthreads();
      tmp[tid] += t;
      __syncthreads();
    }
    if(base + tid < N) offs[base + tid + 1] = running + tmp[tid];
    running += tmp[1023];
  }
}

__global__ void k_scatter(const int* __restrict__ src, const int* __restrict__ dst,
                          const int* __restrict__ offs, int* __restrict__ cur,
                          int* __restrict__ csr, int E){
  int e = blockIdx.x*256 + threadIdx.x;
  if(e < E){
    int d = dst[e];
    int p = offs[d] + atomicAdd(&cur[d], 1);
    if(p >= 0 && p < E) csr[p] = src[e];
  }
}

// ---------------- W transpose+convert: W f32 [128][384] -> Wt bf16 [384][128] -------

__global__ void k_wt(const float* __restrict__ W, bf16* __restrict__ Wt){
  int i = blockIdx.x*256 + threadIdx.x;
  if(i < HEADS*HDIM*HDIM){
    int n = i >> 7, k = i & 127;
    Wt[i] = __float2bfloat16(W[k*(HEADS*HDIM) + n]);
  }
}

// ---------------- GEMM: out[M,384] = A[M,128] @ W[128,384]  (Wt is [384][128]) --------
// block 256 thr = 4 waves (2x2); tile 64 rows x 128 cols; K=128 in 4 MFMA steps.
// AF32: A is float32 (converted to bf16 fragments in-kernel), else bf16.

template<int AF32>
__global__ __launch_bounds__(256) void k_gemm(const void* __restrict__ Av,
                                              const bf16* __restrict__ Wt,
                                              bf16* __restrict__ out, int M){
  int tid  = threadIdx.x;
  int wave = tid >> 6, lane = tid & 63;
  int wr = wave >> 1, wc = wave & 1;
  int row0 = blockIdx.x*64 + wr*32;
  int col0 = blockIdx.y*128 + wc*64;
  int l15 = lane & 15, lhi = lane >> 4;

  f32x4 acc[2][4] = {};
  for(int kk = 0; kk < 4; ++kk){
    int kb = kk*32 + lhi*8;
    v8bf a[2], b[4];
    for(int mi = 0; mi < 2; ++mi){
      int r = row0 + mi*16 + l15;
      if(r >= M) r = M - 1;                 // clamp; stores are guarded
      if constexpr(AF32){
        const float* ap = (const float*)Av + (size_t)r*HDIM + kb;
        f32x4 lo = *reinterpret_cast<const f32x4*>(ap);
        f32x4 hi = *reinterpret_cast<const f32x4*>(ap + 4);
        #pragma unroll
        for(int j = 0; j < 4; ++j){ a[mi][j] = (__bf16)lo[j]; a[mi][4+j] = (__bf16)hi[j]; }
      } else {
        a[mi] = *reinterpret_cast<const v8bf*>((const bf16*)Av + (size_t)r*HDIM + kb);
      }
    }
    for(int ni = 0; ni < 4; ++ni){
      int c = col0 + ni*16 + l15;
      b[ni] = *reinterpret_cast<const v8bf*>(Wt + (size_t)c*HDIM + kb);
    }
    for(int mi = 0; mi < 2; ++mi)
      for(int ni = 0; ni < 4; ++ni)
        acc[mi][ni] = __builtin_amdgcn_mfma_f32_16x16x32_bf16(a[mi], b[ni], acc[mi][ni], 0, 0, 0);
  }
  for(int mi = 0; mi < 2; ++mi){
    int rbase = row0 + mi*16 + lhi*4;
    for(int j = 0; j < 4; ++j){
      int r = rbase + j;
      if(r < M){
        for(int ni = 0; ni < 4; ++ni){
          int c = col0 + ni*16 + l15;
          out[(size_t)r*(HEADS*HDIM) + c] = __float2bfloat16(acc[mi][ni][j]);
        }
      }
    }
  }
}

// ---------------- el/er: one wave per (node, head) ----------------

__global__ void k_elr(const bf16* __restrict__ feat, const float* __restrict__ al,
                      const float* __restrict__ ar, float* __restrict__ el,
                      float* __restrict__ er, int N){
  int w = (blockIdx.x*blockDim.x + threadIdx.x) >> 6;
  int lane = threadIdx.x & 63;
  if(w >= N*HEADS) return;
  int n = w / HEADS, h = w - n*HEADS;
  const bf16*  fr  = feat + (size_t)n*(HEADS*HDIM) + h*HDIM;
  const float* alh = al + h*HDIM;
  const float* arh = ar + h*HDIM;
  float sl = 0.f, sr = 0.f;
  for(int j = 0; j < 2; ++j){
    int d = lane + 64*j;
    float f = __bfloat162float(fr[d]);
    sl += f*alh[d];
    sr += f*arh[d];
  }
  for(int m = 32; m; m >>= 1){ sl += __shfl_xor(sl, m); sr += __shfl_xor(sr, m); }
  if(lane == 0){ el[w] = sl; er[w] = sr; }
}

// ---------------- aggregation: one block (128 thr) per dst node ----------------

__device__ __forceinline__ float lrelu(float x){ return x > 0.f ? x : NEG_SLOPE*x; }

#define AGG_CHUNK 128

__global__ __launch_bounds__(128) void k_agg(const bf16* __restrict__ feat,
                                             const float* __restrict__ el,
                                             const float* __restrict__ er,
                                             const float* __restrict__ bias,
                                             const int* __restrict__ offs,
                                             const int* __restrict__ csr,
                                             bf16* __restrict__ hout){
  int n = blockIdx.x;
  int tid = threadIdx.x;
  __shared__ int   s_src[AGG_CHUNK];
  __shared__ float s_alpha[AGG_CHUNK*3];
  __shared__ float s_ms[8];
  int o0 = offs[n], o1 = offs[n+1];
  int deg = o1 - o0;
  if(deg < 0) deg = 0;                       // defensive
  if(deg > N_EDGES) deg = 0;                 // defensive
  float er0 = er[n*3+0], er1 = er[n*3+1], er2 = er[n*3+2];

  if(tid < 3){ s_ms[tid] = -1e30f; s_ms[3+tid] = 0.f; }
  __syncthreads();

  // Phase A: online softmax stats per head
  for(int base = 0; base < deg; base += AGG_CHUNK){
    int cn = min(AGG_CHUNK, deg - base);
    if(tid < cn){
      unsigned s = (unsigned)csr[o0 + base + tid];
      if(s >= N_NODES) s = 0;                // defensive
      s_alpha[tid*3+0] = lrelu(el[s*3+0] + er0);
      s_alpha[tid*3+1] = lrelu(el[s*3+1] + er1);
      s_alpha[tid*3+2] = lrelu(el[s*3+2] + er2);
    }
    __syncthreads();
    if(tid < 3){
      float m = s_ms[tid], sum = s_ms[3+tid];
      for(int i = 0; i < cn; ++i){
        float x = s_alpha[i*3+tid];
        float mn = fmaxf(m, x);
        sum = sum*__expf(m - mn) + __expf(x - mn);
        m = mn;
      }
      s_ms[tid] = m; s_ms[3+tid] = sum;
    }
    __syncthreads();
  }
  float M0 = s_ms[0], M1 = s_ms[1], M2 = s_ms[2];
  float i0 = 1.f/s_ms[3], i1 = 1.f/s_ms[4], i2 = 1.f/s_ms[5]; // unused if deg==0

  // Phase B: alpha + accumulate
  float a0 = 0.f, a1 = 0.f, a2 = 0.f;
  for(int base = 0; base < deg; base += AGG_CHUNK){
    int cn = min(AGG_CHUNK, deg - base);
    __syncthreads();
    if(tid < cn){
      unsigned s = (unsigned)csr[o0 + base + tid];
      if(s >= N_NODES) s = 0;                // defensive
      s_src[tid] = (int)s;
      s_alpha[tid*3+0] = __expf(lrelu(el[s*3+0] + er0) - M0)*i0;
      s_alpha[tid*3+1] = __expf(lrelu(el[s*3+1] + er1) - M1)*i1;
      s_alpha[tid*3+2] = __expf(lrelu(el[s*3+2] + er2) - M2)*i2;
    }
    __syncthreads();
    for(int i = 0; i < cn; ++i){
      const bf16* fr = feat + (size_t)s_src[i]*(HEADS*HDIM);
      a0 += s_alpha[i*3+0]*__bfloat162float(fr[tid]);
      a1 += s_alpha[i*3+1]*__bfloat162float(fr[HDIM + tid]);
      a2 += s_alpha[i*3+2]*__bfloat162float(fr[2*HDIM + tid]);
    }
  }
  float bsum = bias[tid] + bias[HDIM+tid] + bias[2*HDIM+tid];
  hout[(size_t)n*HDIM + tid] = __float2bfloat16((a0 + a1 + a2 + bsum)*(1.f/3.f));
}

// ---------------- final assembly (OUTPUT IS FLOAT32) ----------------

#define SEQ_SZ   (BB*LL*4*HDIM)          // 2621440
#define SEQR_OFF SEQ_SZ
#define SEQR_SZ  (BB*LL*3*HDIM)          // 1966080
#define SH_OFF   (SEQ_SZ + SEQR_SZ)      // 4587520

__global__ __launch_bounds__(128) void k_assemble(const bf16* __restrict__ h2,
                                                  const float* __restrict__ ent_e,
                                                  const float* __restrict__ rel_e,
                                                  const float* __restrict__ glob,
                                                  const float* __restrict__ sht,
                                                  const int* __restrict__ nid,
                                                  const int* __restrict__ s_tem,
                                                  const int* __restrict__ r_tem,
                                                  float* __restrict__ out){
  int p = blockIdx.x;        // 0..B*L-1
  int d = threadIdx.x;       // 0..127
  int b = p / LL;
  float emb = __bfloat162float(h2[(size_t)nid[p]*HDIM + d]);
  float ent = ent_e[(size_t)s_tem[b]*HDIM + d];
  float rel = rel_e[(size_t)r_tem[b]*HDIM + d];
  float gl  = glob[(size_t)p*HDIM + d];
  size_t so = (size_t)p*(4*HDIM);
  out[so + d] = emb; out[so + HDIM + d] = ent;
  out[so + 2*HDIM + d] = rel; out[so + 3*HDIM + d] = gl;
  size_t ro = SEQR_OFF + (size_t)p*(3*HDIM);
  out[ro + d] = emb; out[ro + HDIM + d] = ent; out[ro + 2*HDIM + d] = gl;
  if(d == 0) out[SH_OFF + p] = sht[p];
}

// ---------------- launch ----------------

extern "C" void kernel_launch(void* const* d_in, const int* in_sizes, int n_in,
                              void* d_out, int out_size, void* d_ws, size_t ws_size,
                              hipStream_t stream){
  const float* node_feat = (const float*)d_in[0];
  const float* W1        = (const float*)d_in[1];
  const float* attn_l1   = (const float*)d_in[2];
  const float* attn_r1   = (const float*)d_in[3];
  const float* b1        = (const float*)d_in[4];
  const float* W2        = (const float*)d_in[5];
  const float* attn_l2   = (const float*)d_in[6];
  const float* attn_r2   = (const float*)d_in[7];
  const float* b2        = (const float*)d_in[8];
  const float* ent_emb   = (const float*)d_in[9];
  const float* rel_emb   = (const float*)d_in[10];
  const float* glob      = (const float*)d_in[11];
  const float* sht       = (const float*)d_in[12];
  const int*  e_src      = (const int*)d_in[13];
  const int*  e_dst      = (const int*)d_in[14];
  const int*  nid        = (const int*)d_in[15];
  const int*  s_tem      = (const int*)d_in[16];
  const int*  r_tem      = (const int*)d_in[17];
  float* out = (float*)d_out;

  // Aliased workspace layout — peak ~55.0 MB.
  char* ws = (char*)d_ws;
  size_t cur_off = 0;
  auto alloc = [&](size_t bytes)->char*{
    char* r = ws + cur_off;
    cur_off += (bytes + 255) & ~(size_t)255;
    return r;
  };
  bf16*  feat = (bf16*) alloc((size_t)N_NODES*HEADS*HDIM*2);
  bf16*  h    = (bf16*) alloc((size_t)N_NODES*HDIM*2);       // h1 and h2
  float* el   = (float*)alloc((size_t)N_NODES*HEADS*4);
  float* er   = (float*)alloc((size_t)N_NODES*HEADS*4);
  bf16*  wt1  = (bf16*) alloc((size_t)HEADS*HDIM*HDIM*2);
  bf16*  wt2  = (bf16*) alloc((size_t)HEADS*HDIM*HDIM*2);
  int*   offs = (int*)  alloc((size_t)(N_NODES+1)*4);
  int*   cnt  = (int*)  alloc((size_t)N_NODES*4);            // also curp
  int*   csr  = (int*)  alloc((size_t)N_EDGES*4);

  // CSR build (shared by both layers)
  k_zero1<<<(N_NODES+255)/256, 256, 0, stream>>>(cnt, N_NODES);
  k_hist<<<(N_EDGES+255)/256, 256, 0, stream>>>(e_dst, cnt, N_EDGES);
  k_scan<<<1, 1024, 0, stream>>>(cnt, offs, N_NODES);
  k_zero1<<<(N_NODES+255)/256, 256, 0, stream>>>(cnt, N_NODES);   // now curp
  k_scatter<<<(N_EDGES+255)/256, 256, 0, stream>>>(e_src, e_dst, offs, cnt, csr, N_EDGES);

  // weight transposes
  k_wt<<<(HEADS*HDIM*HDIM+255)/256, 256, 0, stream>>>(W1, wt1);
  k_wt<<<(HEADS*HDIM*HDIM+255)/256, 256, 0, stream>>>(W2, wt2);

  dim3 ggrid((N_NODES + 63)/64, HEADS);
  int elr_blocks = (N_NODES*HEADS + 3)/4;   // 4 waves per 256-thr block

  // Layer 1 (A = node_feat f32, converted in-kernel)
  k_gemm<1><<<ggrid, 256, 0, stream>>>((const void*)node_feat, wt1, feat, N_NODES);
  k_elr<<<elr_blocks, 256, 0, stream>>>(feat, attn_l1, attn_r1, el, er, N_NODES);
  k_agg<<<N_NODES, 128, 0, stream>>>(feat, el, er, b1, offs, csr, h);

  // Layer 2 (A = h bf16)
  k_gemm<0><<<ggrid, 256, 0, stream>>>((const void*)h, wt2, feat, N_NODES);
  k_elr<<<elr_blocks, 256, 0, stream>>>(feat, attn_l2, attn_r2, el, er, N_NODES);
  k_agg<<<N_NODES, 128, 0, stream>>>(feat, el, er, b2, offs, csr, h);

  // Assembly (f32 output)
  k_assemble<<<BB*LL, 128, 0, stream>>>(h, ent_emb, rel_emb, glob, sht,
                                        nid, s_tem, r_tem, out);
}

// Round 5
// 329.584 us; speedup vs baseline: 1.2308x; 1.2308x over previous
//
#include <hip/hip_runtime.h>
#include <hip/hip_bf16.h>

#define N_NODES 50000
#define N_EDGES 500000
#define HDIM 128
#define HEADS 3
#define BB 512
#define LL 10
#define NEG_SLOPE 0.2f

typedef __hip_bfloat16 bf16;
typedef __bf16 v8bf __attribute__((ext_vector_type(8)));
typedef float f32x4 __attribute__((ext_vector_type(4)));

// ---------------- utility ----------------

__global__ void k_zero1(int* a, int n){
  int i = blockIdx.x*256 + threadIdx.x;
  if(i < n) a[i] = 0;
}

__global__ void k_hist(const int* __restrict__ dst, int* __restrict__ cnt, int E){
  int e = blockIdx.x*256 + threadIdx.x;
  if(e < E) atomicAdd(&cnt[dst[e]], 1);
}

// ---------------- hierarchical scan: cnt[0..N) -> offs[0..N], offs[0]=0 ------
// Phase A: per-block (2048-elem tile) totals. Phase B: 1-wave scan of totals.
// Phase C: block-local scan + block offset -> offs; also zeroes cnt (cursor reuse).

#define SCAN_TILE 2048
#define SCAN_NB ((N_NODES + SCAN_TILE - 1)/SCAN_TILE)   // 25

__global__ __launch_bounds__(256) void k_scan_part(const int* __restrict__ cnt,
                                                   int* __restrict__ bsum){
  int b = blockIdx.x, tid = threadIdx.x;
  int i0 = b*SCAN_TILE + tid*8;
  int s = 0;
  #pragma unroll
  for(int j = 0; j < 8; ++j){ int i = i0 + j; s += (i < N_NODES) ? cnt[i] : 0; }
  for(int m = 32; m; m >>= 1) s += __shfl_xor(s, m);
  __shared__ int ws[4];
  if((tid & 63) == 0) ws[tid >> 6] = s;
  __syncthreads();
  if(tid == 0) bsum[b] = ws[0] + ws[1] + ws[2] + ws[3];
}

__global__ __launch_bounds__(64) void k_scan_top(int* __restrict__ bsum, int nb){
  int tid = threadIdx.x;
  int v = (tid < nb) ? bsum[tid] : 0;
  for(int s = 1; s < 64; s <<= 1){
    int t = __shfl_up(v, s);
    if(tid >= s) v += t;
  }
  if(tid < nb) bsum[tid] = v;   // inclusive scan of block totals
}

__global__ __launch_bounds__(256) void k_scan_write(int* __restrict__ cnt,
                                                    const int* __restrict__ bsum,
                                                    int* __restrict__ offs){
  int b = blockIdx.x, tid = threadIdx.x;
  int lane = tid & 63, wv = tid >> 6;
  int i0 = b*SCAN_TILE + tid*8;
  int v[8]; int s = 0;
  #pragma unroll
  for(int j = 0; j < 8; ++j){
    int i = i0 + j;
    v[j] = (i < N_NODES) ? cnt[i] : 0;
    s += v[j];
  }
  #pragma unroll
  for(int j = 0; j < 8; ++j){ int i = i0 + j; if(i < N_NODES) cnt[i] = 0; }
  // inclusive shfl-scan of per-thread sums within wave
  int incl = s;
  for(int sh = 1; sh < 64; sh <<= 1){
    int t = __shfl_up(incl, sh);
    if(lane >= sh) incl += t;
  }
  __shared__ int wtot[4];
  if(lane == 63) wtot[wv] = incl;
  __syncthreads();
  int woff = 0;
  for(int w = 0; w < wv; ++w) woff += wtot[w];
  int excl = woff + incl - s;                   // exclusive prefix within block
  int run = ((b > 0) ? bsum[b-1] : 0) + excl;   // global exclusive prefix
  #pragma unroll
  for(int j = 0; j < 8; ++j){
    int i = i0 + j;
    run += v[j];
    if(i < N_NODES) offs[i+1] = run;
  }
  if(b == 0 && tid == 0) offs[0] = 0;
}

__global__ void k_scatter(const int* __restrict__ src, const int* __restrict__ dst,
                          const int* __restrict__ offs, int* __restrict__ cur,
                          int* __restrict__ csr, int E){
  int e = blockIdx.x*256 + threadIdx.x;
  if(e < E){
    int d = dst[e];
    int p = offs[d] + atomicAdd(&cur[d], 1);
    if(p >= 0 && p < E) csr[p] = src[e];
  }
}

// ---------------- W transpose+convert: W f32 [128][384] -> Wt bf16 [384][128] -------

__global__ void k_wt(const float* __restrict__ W, bf16* __restrict__ Wt){
  int i = blockIdx.x*256 + threadIdx.x;
  if(i < HEADS*HDIM*HDIM){
    int n = i >> 7, k = i & 127;
    Wt[i] = __float2bfloat16(W[k*(HEADS*HDIM) + n]);
  }
}

// ---------------- GEMM: out[M,384] = A[M,128] @ W[128,384]  (Wt is [384][128]) --------

template<int AF32>
__global__ __launch_bounds__(256) void k_gemm(const void* __restrict__ Av,
                                              const bf16* __restrict__ Wt,
                                              bf16* __restrict__ out, int M){
  int tid  = threadIdx.x;
  int wave = tid >> 6, lane = tid & 63;
  int wr = wave >> 1, wc = wave & 1;
  int row0 = blockIdx.x*64 + wr*32;
  int col0 = blockIdx.y*128 + wc*64;
  int l15 = lane & 15, lhi = lane >> 4;

  f32x4 acc[2][4] = {};
  for(int kk = 0; kk < 4; ++kk){
    int kb = kk*32 + lhi*8;
    v8bf a[2], b[4];
    for(int mi = 0; mi < 2; ++mi){
      int r = row0 + mi*16 + l15;
      if(r >= M) r = M - 1;                 // clamp; stores are guarded
      if constexpr(AF32){
        const float* ap = (const float*)Av + (size_t)r*HDIM + kb;
        f32x4 lo = *reinterpret_cast<const f32x4*>(ap);
        f32x4 hi = *reinterpret_cast<const f32x4*>(ap + 4);
        #pragma unroll
        for(int j = 0; j < 4; ++j){ a[mi][j] = (__bf16)lo[j]; a[mi][4+j] = (__bf16)hi[j]; }
      } else {
        a[mi] = *reinterpret_cast<const v8bf*>((const bf16*)Av + (size_t)r*HDIM + kb);
      }
    }
    for(int ni = 0; ni < 4; ++ni){
      int c = col0 + ni*16 + l15;
      b[ni] = *reinterpret_cast<const v8bf*>(Wt + (size_t)c*HDIM + kb);
    }
    for(int mi = 0; mi < 2; ++mi)
      for(int ni = 0; ni < 4; ++ni)
        acc[mi][ni] = __builtin_amdgcn_mfma_f32_16x16x32_bf16(a[mi], b[ni], acc[mi][ni], 0, 0, 0);
  }
  for(int mi = 0; mi < 2; ++mi){
    int rbase = row0 + mi*16 + lhi*4;
    for(int j = 0; j < 4; ++j){
      int r = rbase + j;
      if(r < M){
        for(int ni = 0; ni < 4; ++ni){
          int c = col0 + ni*16 + l15;
          out[(size_t)r*(HEADS*HDIM) + c] = __float2bfloat16(acc[mi][ni][j]);
        }
      }
    }
  }
}

// ---------------- el/er: one wave per (node, head) ----------------

__global__ void k_elr(const bf16* __restrict__ feat, const float* __restrict__ al,
                      const float* __restrict__ ar, float* __restrict__ el,
                      float* __restrict__ er, int N){
  int w = (blockIdx.x*blockDim.x + threadIdx.x) >> 6;
  int lane = threadIdx.x & 63;
  if(w >= N*HEADS) return;
  int n = w / HEADS, h = w - n*HEADS;
  const bf16*  fr  = feat + (size_t)n*(HEADS*HDIM) + h*HDIM;
  const float* alh = al + h*HDIM;
  const float* arh = ar + h*HDIM;
  float sl = 0.f, sr = 0.f;
  for(int j = 0; j < 2; ++j){
    int d = lane + 64*j;
    float f = __bfloat162float(fr[d]);
    sl += f*alh[d];
    sr += f*arh[d];
  }
  for(int m = 32; m; m >>= 1){ sl += __shfl_xor(sl, m); sr += __shfl_xor(sr, m); }
  if(lane == 0){ el[w] = sl; er[w] = sr; }
}

// ---------------- aggregation: one block (128 thr) per dst node ----------------

__device__ __forceinline__ float lrelu(float x){ return x > 0.f ? x : NEG_SLOPE*x; }

#define AGG_CHUNK 128

__global__ __launch_bounds__(128) void k_agg(const bf16* __restrict__ feat,
                                             const float* __restrict__ el,
                                             const float* __restrict__ er,
                                             const float* __restrict__ bias,
                                             const int* __restrict__ offs,
                                             const int* __restrict__ csr,
                                             bf16* __restrict__ hout){
  int n = blockIdx.x;
  int tid = threadIdx.x;
  __shared__ int   s_src[AGG_CHUNK];
  __shared__ float s_alpha[AGG_CHUNK*3];
  __shared__ float s_ms[8];
  int o0 = offs[n], o1 = offs[n+1];
  int deg = o1 - o0;
  if(deg < 0) deg = 0;
  if(deg > N_EDGES) deg = 0;
  float er0 = er[n*3+0], er1 = er[n*3+1], er2 = er[n*3+2];

  if(tid < 3){ s_ms[tid] = -1e30f; s_ms[3+tid] = 0.f; }
  __syncthreads();

  // Phase A: online softmax stats per head
  for(int base = 0; base < deg; base += AGG_CHUNK){
    int cn = min(AGG_CHUNK, deg - base);
    if(tid < cn){
      unsigned s = (unsigned)csr[o0 + base + tid];
      if(s >= N_NODES) s = 0;
      s_alpha[tid*3+0] = lrelu(el[s*3+0] + er0);
      s_alpha[tid*3+1] = lrelu(el[s*3+1] + er1);
      s_alpha[tid*3+2] = lrelu(el[s*3+2] + er2);
    }
    __syncthreads();
    if(tid < 3){
      float m = s_ms[tid], sum = s_ms[3+tid];
      for(int i = 0; i < cn; ++i){
        float x = s_alpha[i*3+tid];
        float mn = fmaxf(m, x);
        sum = sum*__expf(m - mn) + __expf(x - mn);
        m = mn;
      }
      s_ms[tid] = m; s_ms[3+tid] = sum;
    }
    __syncthreads();
  }
  float M0 = s_ms[0], M1 = s_ms[1], M2 = s_ms[2];
  float i0 = 1.f/s_ms[3], i1 = 1.f/s_ms[4], i2 = 1.f/s_ms[5];

  // Phase B: alpha + accumulate
  float a0 = 0.f, a1 = 0.f, a2 = 0.f;
  for(int base = 0; base < deg; base += AGG_CHUNK){
    int cn = min(AGG_CHUNK, deg - base);
    __syncthreads();
    if(tid < cn){
      unsigned s = (unsigned)csr[o0 + base + tid];
      if(s >= N_NODES) s = 0;
      s_src[tid] = (int)s;
      s_alpha[tid*3+0] = __expf(lrelu(el[s*3+0] + er0) - M0)*i0;
      s_alpha[tid*3+1] = __expf(lrelu(el[s*3+1] + er1) - M1)*i1;
      s_alpha[tid*3+2] = __expf(lrelu(el[s*3+2] + er2) - M2)*i2;
    }
    __syncthreads();
    for(int i = 0; i < cn; ++i){
      const bf16* fr = feat + (size_t)s_src[i]*(HEADS*HDIM);
      a0 += s_alpha[i*3+0]*__bfloat162float(fr[tid]);
      a1 += s_alpha[i*3+1]*__bfloat162float(fr[HDIM + tid]);
      a2 += s_alpha[i*3+2]*__bfloat162float(fr[2*HDIM + tid]);
    }
  }
  float bsum = bias[tid] + bias[HDIM+tid] + bias[2*HDIM+tid];
  hout[(size_t)n*HDIM + tid] = __float2bfloat16((a0 + a1 + a2 + bsum)*(1.f/3.f));
}

// ---------------- final assembly (f32 output) ----------------

#define SEQ_SZ   (BB*LL*4*HDIM)
#define SEQR_OFF SEQ_SZ
#define SEQR_SZ  (BB*LL*3*HDIM)
#define SH_OFF   (SEQ_SZ + SEQR_SZ)

__global__ __launch_bounds__(128) void k_assemble(const bf16* __restrict__ h2,
                                                  const float* __restrict__ ent_e,
                                                  const float* __restrict__ rel_e,
                                                  const float* __restrict__ glob,
                                                  const float* __restrict__ sht,
                                                  const int* __restrict__ nid,
                                                  const int* __restrict__ s_tem,
                                                  const int* __restrict__ r_tem,
                                                  float* __restrict__ out){
  int p = blockIdx.x;
  int d = threadIdx.x;
  int b = p / LL;
  float emb = __bfloat162float(h2[(size_t)nid[p]*HDIM + d]);
  float ent = ent_e[(size_t)s_tem[b]*HDIM + d];
  float rel = rel_e[(size_t)r_tem[b]*HDIM + d];
  float gl  = glob[(size_t)p*HDIM + d];
  size_t so = (size_t)p*(4*HDIM);
  out[so + d] = emb; out[so + HDIM + d] = ent;
  out[so + 2*HDIM + d] = rel; out[so + 3*HDIM + d] = gl;
  size_t ro = SEQR_OFF + (size_t)p*(3*HDIM);
  out[ro + d] = emb; out[ro + HDIM + d] = ent; out[ro + 2*HDIM + d] = gl;
  if(d == 0) out[SH_OFF + p] = sht[p];
}

// ---------------- launch ----------------

extern "C" void kernel_launch(void* const* d_in, const int* in_sizes, int n_in,
                              void* d_out, int out_size, void* d_ws, size_t ws_size,
                              hipStream_t stream){
  const float* node_feat = (const float*)d_in[0];
  const float* W1        = (const float*)d_in[1];
  const float* attn_l1   = (const float*)d_in[2];
  const float* attn_r1   = (const float*)d_in[3];
  const float* b1        = (const float*)d_in[4];
  const float* W2        = (const float*)d_in[5];
  const float* attn_l2   = (const float*)d_in[6];
  const float* attn_r2   = (const float*)d_in[7];
  const float* b2        = (const float*)d_in[8];
  const float* ent_emb   = (const float*)d_in[9];
  const float* rel_emb   = (const float*)d_in[10];
  const float* glob      = (const float*)d_in[11];
  const float* sht       = (const float*)d_in[12];
  const int*  e_src      = (const int*)d_in[13];
  const int*  e_dst      = (const int*)d_in[14];
  const int*  nid        = (const int*)d_in[15];
  const int*  s_tem      = (const int*)d_in[16];
  const int*  r_tem      = (const int*)d_in[17];
  float* out = (float*)d_out;

  char* ws = (char*)d_ws;
  size_t cur_off = 0;
  auto alloc = [&](size_t bytes)->char*{
    char* r = ws + cur_off;
    cur_off += (bytes + 255) & ~(size_t)255;
    return r;
  };
  bf16*  feat = (bf16*) alloc((size_t)N_NODES*HEADS*HDIM*2);
  bf16*  h    = (bf16*) alloc((size_t)N_NODES*HDIM*2);       // h1 and h2
  float* el   = (float*)alloc((size_t)N_NODES*HEADS*4);
  float* er   = (float*)alloc((size_t)N_NODES*HEADS*4);
  bf16*  wt1  = (bf16*) alloc((size_t)HEADS*HDIM*HDIM*2);
  bf16*  wt2  = (bf16*) alloc((size_t)HEADS*HDIM*HDIM*2);
  int*   offs = (int*)  alloc((size_t)(N_NODES+1)*4);
  int*   cnt  = (int*)  alloc((size_t)N_NODES*4);            // also cursor
  int*   bsum = (int*)  alloc((size_t)SCAN_NB*4);
  int*   csr  = (int*)  alloc((size_t)N_EDGES*4);

  // CSR build (shared by both layers)
  k_zero1<<<(N_NODES+255)/256, 256, 0, stream>>>(cnt, N_NODES);
  k_hist<<<(N_EDGES+255)/256, 256, 0, stream>>>(e_dst, cnt, N_EDGES);
  k_scan_part<<<SCAN_NB, 256, 0, stream>>>(cnt, bsum);
  k_scan_top<<<1, 64, 0, stream>>>(bsum, SCAN_NB);
  k_scan_write<<<SCAN_NB, 256, 0, stream>>>(cnt, bsum, offs);   // also zeroes cnt
  k_scatter<<<(N_EDGES+255)/256, 256, 0, stream>>>(e_src, e_dst, offs, cnt, csr, N_EDGES);

  // weight transposes
  k_wt<<<(HEADS*HDIM*HDIM+255)/256, 256, 0, stream>>>(W1, wt1);
  k_wt<<<(HEADS*HDIM*HDIM+255)/256, 256, 0, stream>>>(W2, wt2);

  dim3 ggrid((N_NODES + 63)/64, HEADS);
  int elr_blocks = (N_NODES*HEADS + 3)/4;

  // Layer 1 (A = node_feat f32, converted in-kernel)
  k_gemm<1><<<ggrid, 256, 0, stream>>>((const void*)node_feat, wt1, feat, N_NODES);
  k_elr<<<elr_blocks, 256, 0, stream>>>(feat, attn_l1, attn_r1, el, er, N_NODES);
  k_agg<<<N_NODES, 128, 0, stream>>>(feat, el, er, b1, offs, csr, h);

  // Layer 2 (A = h bf16)
  k_gemm<0><<<ggrid, 256, 0, stream>>>((const void*)h, wt2, feat, N_NODES);
  k_elr<<<elr_blocks, 256, 0, stream>>>(feat, attn_l2, attn_r2, el, er, N_NODES);
  k_agg<<<N_NODES, 128, 0, stream>>>(feat, el, er, b2, offs, csr, h);

  // Assembly (f32 output)
  k_assemble<<<BB*LL, 128, 0, stream>>>(h, ent_emb, rel_emb, glob, sht,
                                        nid, s_tem, r_tem, out);
}

// Round 6
// 229.373 us; speedup vs baseline: 1.7685x; 1.4369x over previous
//
#include <hip/hip_runtime.h>
#include <hip/hip_bf16.h>

#define N_NODES 50000
#define N_EDGES 500000
#define HDIM 128
#define HEADS 3
#define BB 512
#define LL 10
#define NEG_SLOPE 0.2f

typedef __hip_bfloat16 bf16;
typedef unsigned char fp8t;
typedef __bf16 v8bf __attribute__((ext_vector_type(8)));
typedef float f32x4 __attribute__((ext_vector_type(4)));

// ---------------- utility ----------------

__global__ void k_zero1(int* a, int n){
  int i = blockIdx.x*256 + threadIdx.x;
  if(i < n) a[i] = 0;
}

__global__ void k_hist(const int* __restrict__ dst, int* __restrict__ cnt, int E){
  int e = blockIdx.x*256 + threadIdx.x;
  if(e < E) atomicAdd(&cnt[dst[e]], 1);
}

// ---------------- hierarchical scan: cnt[0..N) -> offs[0..N], offs[0]=0 ------

#define SCAN_TILE 2048
#define SCAN_NB ((N_NODES + SCAN_TILE - 1)/SCAN_TILE)   // 25

__global__ __launch_bounds__(256) void k_scan_part(const int* __restrict__ cnt,
                                                   int* __restrict__ bsum){
  int b = blockIdx.x, tid = threadIdx.x;
  int i0 = b*SCAN_TILE + tid*8;
  int s = 0;
  #pragma unroll
  for(int j = 0; j < 8; ++j){ int i = i0 + j; s += (i < N_NODES) ? cnt[i] : 0; }
  for(int m = 32; m; m >>= 1) s += __shfl_xor(s, m);
  __shared__ int ws[4];
  if((tid & 63) == 0) ws[tid >> 6] = s;
  __syncthreads();
  if(tid == 0) bsum[b] = ws[0] + ws[1] + ws[2] + ws[3];
}

__global__ __launch_bounds__(64) void k_scan_top(int* __restrict__ bsum, int nb){
  int tid = threadIdx.x;
  int v = (tid < nb) ? bsum[tid] : 0;
  for(int s = 1; s < 64; s <<= 1){
    int t = __shfl_up(v, s);
    if(tid >= s) v += t;
  }
  if(tid < nb) bsum[tid] = v;
}

__global__ __launch_bounds__(256) void k_scan_write(int* __restrict__ cnt,
                                                    const int* __restrict__ bsum,
                                                    int* __restrict__ offs){
  int b = blockIdx.x, tid = threadIdx.x;
  int lane = tid & 63, wv = tid >> 6;
  int i0 = b*SCAN_TILE + tid*8;
  int v[8]; int s = 0;
  #pragma unroll
  for(int j = 0; j < 8; ++j){
    int i = i0 + j;
    v[j] = (i < N_NODES) ? cnt[i] : 0;
    s += v[j];
  }
  #pragma unroll
  for(int j = 0; j < 8; ++j){ int i = i0 + j; if(i < N_NODES) cnt[i] = 0; }
  int incl = s;
  for(int sh = 1; sh < 64; sh <<= 1){
    int t = __shfl_up(incl, sh);
    if(lane >= sh) incl += t;
  }
  __shared__ int wtot[4];
  if(lane == 63) wtot[wv] = incl;
  __syncthreads();
  int woff = 0;
  for(int w = 0; w < wv; ++w) woff += wtot[w];
  int excl = woff + incl - s;
  int run = ((b > 0) ? bsum[b-1] : 0) + excl;
  #pragma unroll
  for(int j = 0; j < 8; ++j){
    int i = i0 + j;
    run += v[j];
    if(i < N_NODES) offs[i+1] = run;
  }
  if(b == 0 && tid == 0) offs[0] = 0;
}

__global__ void k_scatter(const int* __restrict__ src, const int* __restrict__ dst,
                          const int* __restrict__ offs, int* __restrict__ cur,
                          int* __restrict__ csr, int E){
  int e = blockIdx.x*256 + threadIdx.x;
  if(e < E){
    int d = dst[e];
    int p = offs[d] + atomicAdd(&cur[d], 1);
    if(p >= 0 && p < E) csr[p] = src[e];
  }
}

// ---------------- W transpose+convert: W f32 [128][384] -> Wt bf16 [384][128] -------

__global__ void k_wt(const float* __restrict__ W, bf16* __restrict__ Wt){
  int i = blockIdx.x*256 + threadIdx.x;
  if(i < HEADS*HDIM*HDIM){
    int n = i >> 7, k = i & 127;
    Wt[i] = __float2bfloat16(W[k*(HEADS*HDIM) + n]);
  }
}

// ---------------- GEMM + fused el/er + fp8 feat write ----------------
// block 256 thr = 4 waves (2x2); tile 64 rows x 128 cols (one full head).
// Epilogue: el/er from f32 acc via shfl+LDS reduce; acc -> fp8 e4m3 feat.

template<int AF32>
__global__ __launch_bounds__(256) void k_gemm(const void* __restrict__ Av,
                                              const bf16* __restrict__ Wt,
                                              const float* __restrict__ al,
                                              const float* __restrict__ ar,
                                              fp8t* __restrict__ feat8,
                                              float* __restrict__ el,
                                              float* __restrict__ er, int M){
  int tid  = threadIdx.x;
  int wave = tid >> 6, lane = tid & 63;
  int wr = wave >> 1, wc = wave & 1;
  int row0 = blockIdx.x*64 + wr*32;
  int col0 = blockIdx.y*128 + wc*64;
  int l15 = lane & 15, lhi = lane >> 4;

  f32x4 acc[2][4] = {};
  for(int kk = 0; kk < 4; ++kk){
    int kb = kk*32 + lhi*8;
    v8bf a[2], b[4];
    for(int mi = 0; mi < 2; ++mi){
      int r = row0 + mi*16 + l15;
      if(r >= M) r = M - 1;                 // clamp; stores are guarded
      if constexpr(AF32){
        const float* ap = (const float*)Av + (size_t)r*HDIM + kb;
        f32x4 lo = *reinterpret_cast<const f32x4*>(ap);
        f32x4 hi = *reinterpret_cast<const f32x4*>(ap + 4);
        #pragma unroll
        for(int j = 0; j < 4; ++j){ a[mi][j] = (__bf16)lo[j]; a[mi][4+j] = (__bf16)hi[j]; }
      } else {
        a[mi] = *reinterpret_cast<const v8bf*>((const bf16*)Av + (size_t)r*HDIM + kb);
      }
    }
    for(int ni = 0; ni < 4; ++ni){
      int c = col0 + ni*16 + l15;
      b[ni] = *reinterpret_cast<const v8bf*>(Wt + (size_t)c*HDIM + kb);
    }
    for(int mi = 0; mi < 2; ++mi)
      for(int ni = 0; ni < 4; ++ni)
        acc[mi][ni] = __builtin_amdgcn_mfma_f32_16x16x32_bf16(a[mi], b[ni], acc[mi][ni], 0, 0, 0);
  }

  // ---- fused el/er reduction (f32, from accumulators) ----
  const float* alh = al + blockIdx.y*HDIM;
  const float* arh = ar + blockIdx.y*HDIM;
  float alv[4], arv[4];
  #pragma unroll
  for(int ni = 0; ni < 4; ++ni){
    int d = wc*64 + ni*16 + l15;
    alv[ni] = alh[d]; arv[ni] = arh[d];
  }
  __shared__ float red[2][64][2];          // [wc][row][el/er]
  __shared__ int4 tile4[512];              // 64 x 128 fp8 bytes
  fp8t* tile8 = (fp8t*)tile4;

  #pragma unroll
  for(int mi = 0; mi < 2; ++mi){
    #pragma unroll
    for(int j = 0; j < 4; ++j){
      float pe = 0.f, pr = 0.f;
      #pragma unroll
      for(int ni = 0; ni < 4; ++ni){
        pe += acc[mi][ni][j]*alv[ni];
        pr += acc[mi][ni][j]*arv[ni];
      }
      for(int k = 8; k; k >>= 1){ pe += __shfl_xor(pe, k); pr += __shfl_xor(pr, k); }
      int row_l = wr*32 + mi*16 + lhi*4 + j;
      if(l15 == 0){ red[wc][row_l][0] = pe; red[wc][row_l][1] = pr; }
    }
  }
  // ---- fp8 convert into LDS tile ----
  #pragma unroll
  for(int mi = 0; mi < 2; ++mi)
    #pragma unroll
    for(int j = 0; j < 4; ++j){
      int row_l = wr*32 + mi*16 + lhi*4 + j;
      #pragma unroll
      for(int ni = 0; ni < 4; ++ni){
        float x = acc[mi][ni][j];
        unsigned bb = (unsigned)__builtin_amdgcn_cvt_pk_fp8_f32(x, x, 0, false) & 0xFFu;
        tile8[row_l*128 + wc*64 + ni*16 + l15] = (fp8t)bb;
      }
    }
  __syncthreads();

  if(tid < 64){
    int r = blockIdx.x*64 + tid;
    if(r < M){
      el[r*3 + blockIdx.y] = red[0][tid][0] + red[1][tid][0];
      er[r*3 + blockIdx.y] = red[0][tid][1] + red[1][tid][1];
    }
  }
  #pragma unroll
  for(int pass = 0; pass < 2; ++pass){
    int off = pass*4096 + tid*16;
    int row_l = off >> 7, col = off & 127;
    int r = blockIdx.x*64 + row_l;
    if(r < M)
      *reinterpret_cast<int4*>(feat8 + (size_t)r*(HEADS*HDIM) + blockIdx.y*HDIM + col) =
          tile4[off >> 4];
  }
}

// ---------------- aggregation: one block (128 thr) per dst node ----------------
// Parallel softmax reductions; fp8 feat gathers; optional node-list + f32 out.

__device__ __forceinline__ float lrelu(float x){ return x > 0.f ? x : NEG_SLOPE*x; }
__device__ __forceinline__ float cvt8(fp8t b){
  return __builtin_amdgcn_cvt_f32_fp8((int)b, 0);
}

#define AGG_CHUNK 128

template<int USE_LIST, int OUT_F32>
__global__ __launch_bounds__(128) void k_agg(const fp8t* __restrict__ feat8,
                                             const float* __restrict__ el,
                                             const float* __restrict__ er,
                                             const float* __restrict__ bias,
                                             const int* __restrict__ offs,
                                             const int* __restrict__ csr,
                                             const int* __restrict__ list,
                                             void* __restrict__ hout){
  int bid = blockIdx.x;
  int n = USE_LIST ? list[bid] : bid;
  int tid = threadIdx.x, lane = tid & 63, wv = tid >> 6;
  __shared__ float s_m[2][3], s_s[2][3];
  __shared__ float s_alpha[AGG_CHUNK][4];
  __shared__ int   s_src[AGG_CHUNK];
  int o0 = offs[n];
  int deg = offs[n+1] - o0;
  if(deg < 0 || deg > N_EDGES) deg = 0;
  float er0 = er[n*3+0], er1 = er[n*3+1], er2 = er[n*3+2];

  float M0 = -1e30f, M1 = -1e30f, M2 = -1e30f;
  float S0 = 0.f, S1 = 0.f, S2 = 0.f;
  float cx0 = 0.f, cx1 = 0.f, cx2 = 0.f; int cs = 0;   // first-chunk reg cache

  for(int base = 0; base < deg; base += AGG_CHUNK){
    int cn = min(AGG_CHUNK, deg - base);
    float x0 = -1e30f, x1 = -1e30f, x2 = -1e30f; int s = 0;
    if(tid < cn){
      unsigned su = (unsigned)csr[o0 + base + tid];
      if(su >= N_NODES) su = 0;
      s = (int)su;
      x0 = lrelu(el[s*3+0] + er0);
      x1 = lrelu(el[s*3+1] + er1);
      x2 = lrelu(el[s*3+2] + er2);
    }
    if(base == 0){ cx0 = x0; cx1 = x1; cx2 = x2; cs = s; }
    float m0 = x0, m1 = x1, m2 = x2;
    for(int k = 32; k; k >>= 1){
      m0 = fmaxf(m0, __shfl_xor(m0, k));
      m1 = fmaxf(m1, __shfl_xor(m1, k));
      m2 = fmaxf(m2, __shfl_xor(m2, k));
    }
    if(lane == 0){ s_m[wv][0] = m0; s_m[wv][1] = m1; s_m[wv][2] = m2; }
    __syncthreads();
    float nm0 = fmaxf(M0, fmaxf(s_m[0][0], s_m[1][0]));
    float nm1 = fmaxf(M1, fmaxf(s_m[0][1], s_m[1][1]));
    float nm2 = fmaxf(M2, fmaxf(s_m[0][2], s_m[1][2]));
    float e0 = (tid < cn) ? __expf(x0 - nm0) : 0.f;
    float e1 = (tid < cn) ? __expf(x1 - nm1) : 0.f;
    float e2 = (tid < cn) ? __expf(x2 - nm2) : 0.f;
    for(int k = 32; k; k >>= 1){
      e0 += __shfl_xor(e0, k); e1 += __shfl_xor(e1, k); e2 += __shfl_xor(e2, k);
    }
    if(lane == 0){ s_s[wv][0] = e0; s_s[wv][1] = e1; s_s[wv][2] = e2; }
    __syncthreads();
    S0 = S0*__expf(M0 - nm0) + s_s[0][0] + s_s[1][0];
    S1 = S1*__expf(M1 - nm1) + s_s[0][1] + s_s[1][1];
    S2 = S2*__expf(M2 - nm2) + s_s[0][2] + s_s[1][2];
    M0 = nm0; M1 = nm1; M2 = nm2;
  }
  float i0 = 1.f/S0, i1 = 1.f/S1, i2 = 1.f/S2;   // unused if deg==0

  float a0 = 0.f, a1 = 0.f, a2 = 0.f;
  for(int base = 0; base < deg; base += AGG_CHUNK){
    int cn = min(AGG_CHUNK, deg - base);
    __syncthreads();
    if(tid < cn){
      int s; float x0, x1, x2;
      if(base == 0){ s = cs; x0 = cx0; x1 = cx1; x2 = cx2; }
      else {
        unsigned su = (unsigned)csr[o0 + base + tid];
        if(su >= N_NODES) su = 0;
        s = (int)su;
        x0 = lrelu(el[s*3+0] + er0);
        x1 = lrelu(el[s*3+1] + er1);
        x2 = lrelu(el[s*3+2] + er2);
      }
      s_src[tid] = s;
      s_alpha[tid][0] = __expf(x0 - M0)*i0;
      s_alpha[tid][1] = __expf(x1 - M1)*i1;
      s_alpha[tid][2] = __expf(x2 - M2)*i2;
    }
    __syncthreads();
    for(int i = 0; i < cn; ++i){
      const fp8t* fr = feat8 + (size_t)s_src[i]*(HEADS*HDIM);
      float al0 = s_alpha[i][0], al1 = s_alpha[i][1], al2 = s_alpha[i][2];
      a0 += al0*cvt8(fr[tid]);
      a1 += al1*cvt8(fr[HDIM + tid]);
      a2 += al2*cvt8(fr[2*HDIM + tid]);
    }
  }
  float r = (a0 + a1 + a2 + bias[tid] + bias[HDIM+tid] + bias[2*HDIM+tid])*(1.f/3.f);
  if(OUT_F32) ((float*)hout)[(size_t)bid*HDIM + tid] = r;
  else        ((bf16*)hout)[(size_t)bid*HDIM + tid] = __float2bfloat16(r);
}

// ---------------- final assembly (f32 output) ----------------

#define SEQ_SZ   (BB*LL*4*HDIM)
#define SEQR_OFF SEQ_SZ
#define SEQR_SZ  (BB*LL*3*HDIM)
#define SH_OFF   (SEQ_SZ + SEQR_SZ)

__global__ __launch_bounds__(128) void k_assemble(const float* __restrict__ h2s,
                                                  const float* __restrict__ ent_e,
                                                  const float* __restrict__ rel_e,
                                                  const float* __restrict__ glob,
                                                  const float* __restrict__ sht,
                                                  const int* __restrict__ s_tem,
                                                  const int* __restrict__ r_tem,
                                                  float* __restrict__ out){
  int p = blockIdx.x;
  int d = threadIdx.x;
  int b = p / LL;
  float emb = h2s[(size_t)p*HDIM + d];
  float ent = ent_e[(size_t)s_tem[b]*HDIM + d];
  float rel = rel_e[(size_t)r_tem[b]*HDIM + d];
  float gl  = glob[(size_t)p*HDIM + d];
  size_t so = (size_t)p*(4*HDIM);
  out[so + d] = emb; out[so + HDIM + d] = ent;
  out[so + 2*HDIM + d] = rel; out[so + 3*HDIM + d] = gl;
  size_t ro = SEQR_OFF + (size_t)p*(3*HDIM);
  out[ro + d] = emb; out[ro + HDIM + d] = ent; out[ro + 2*HDIM + d] = gl;
  if(d == 0) out[SH_OFF + p] = sht[p];
}

// ---------------- launch ----------------

extern "C" void kernel_launch(void* const* d_in, const int* in_sizes, int n_in,
                              void* d_out, int out_size, void* d_ws, size_t ws_size,
                              hipStream_t stream){
  const float* node_feat = (const float*)d_in[0];
  const float* W1        = (const float*)d_in[1];
  const float* attn_l1   = (const float*)d_in[2];
  const float* attn_r1   = (const float*)d_in[3];
  const float* b1        = (const float*)d_in[4];
  const float* W2        = (const float*)d_in[5];
  const float* attn_l2   = (const float*)d_in[6];
  const float* attn_r2   = (const float*)d_in[7];
  const float* b2        = (const float*)d_in[8];
  const float* ent_emb   = (const float*)d_in[9];
  const float* rel_emb   = (const float*)d_in[10];
  const float* glob      = (const float*)d_in[11];
  const float* sht       = (const float*)d_in[12];
  const int*  e_src      = (const int*)d_in[13];
  const int*  e_dst      = (const int*)d_in[14];
  const int*  nid        = (const int*)d_in[15];
  const int*  s_tem      = (const int*)d_in[16];
  const int*  r_tem      = (const int*)d_in[17];
  float* out = (float*)d_out;

  char* ws = (char*)d_ws;
  size_t cur_off = 0;
  auto alloc = [&](size_t bytes)->char*{
    char* r = ws + cur_off;
    cur_off += (bytes + 255) & ~(size_t)255;
    return r;
  };
  fp8t*  feat8 = (fp8t*) alloc((size_t)N_NODES*HEADS*HDIM);      // 19.2 MB
  bf16*  h1    = (bf16*) alloc((size_t)N_NODES*HDIM*2);          // 12.8 MB
  float* h2s   = (float*)alloc((size_t)BB*LL*HDIM*4);            // 2.6 MB
  float* el    = (float*)alloc((size_t)N_NODES*HEADS*4);
  float* er    = (float*)alloc((size_t)N_NODES*HEADS*4);
  bf16*  wt1   = (bf16*) alloc((size_t)HEADS*HDIM*HDIM*2);
  bf16*  wt2   = (bf16*) alloc((size_t)HEADS*HDIM*HDIM*2);
  int*   offs  = (int*)  alloc((size_t)(N_NODES+1)*4);
  int*   cnt   = (int*)  alloc((size_t)N_NODES*4);               // also cursor
  int*   bsum  = (int*)  alloc((size_t)SCAN_NB*4);
  int*   csr   = (int*)  alloc((size_t)N_EDGES*4);

  // CSR build (shared by both layers)
  k_zero1<<<(N_NODES+255)/256, 256, 0, stream>>>(cnt, N_NODES);
  k_hist<<<(N_EDGES+255)/256, 256, 0, stream>>>(e_dst, cnt, N_EDGES);
  k_scan_part<<<SCAN_NB, 256, 0, stream>>>(cnt, bsum);
  k_scan_top<<<1, 64, 0, stream>>>(bsum, SCAN_NB);
  k_scan_write<<<SCAN_NB, 256, 0, stream>>>(cnt, bsum, offs);   // also zeroes cnt
  k_scatter<<<(N_EDGES+255)/256, 256, 0, stream>>>(e_src, e_dst, offs, cnt, csr, N_EDGES);

  // weight transposes
  k_wt<<<(HEADS*HDIM*HDIM+255)/256, 256, 0, stream>>>(W1, wt1);
  k_wt<<<(HEADS*HDIM*HDIM+255)/256, 256, 0, stream>>>(W2, wt2);

  dim3 ggrid((N_NODES + 63)/64, HEADS);

  // Layer 1
  k_gemm<1><<<ggrid, 256, 0, stream>>>((const void*)node_feat, wt1, attn_l1, attn_r1,
                                       feat8, el, er, N_NODES);
  k_agg<0,0><<<N_NODES, 128, 0, stream>>>(feat8, el, er, b1, offs, csr, nullptr, (void*)h1);

  // Layer 2 (agg only over the nodes assemble needs)
  k_gemm<0><<<ggrid, 256, 0, stream>>>((const void*)h1, wt2, attn_l2, attn_r2,
                                       feat8, el, er, N_NODES);
  k_agg<1,1><<<BB*LL, 128, 0, stream>>>(feat8, el, er, b2, offs, csr, nid, (void*)h2s);

  // Assembly (f32 output)
  k_assemble<<<BB*LL, 128, 0, stream>>>(h2s, ent_emb, rel_emb, glob, sht,
                                        s_tem, r_tem, out);
}

// Round 7
// 212.758 us; speedup vs baseline: 1.9066x; 1.0781x over previous
//
#include <hip/hip_runtime.h>
#include <hip/hip_bf16.h>

#define N_NODES 50000
#define N_EDGES 500000
#define HDIM 128
#define HEADS 3
#define BB 512
#define LL 10
#define NEG_SLOPE 0.2f

typedef __hip_bfloat16 bf16;
typedef unsigned char fp8t;
typedef __bf16 v8bf __attribute__((ext_vector_type(8)));
typedef float f32x4 __attribute__((ext_vector_type(4)));

// ---------------- utility ----------------

__global__ void k_zero2(int* a, int na, int* b, int nb){
  int i = blockIdx.x*256 + threadIdx.x;
  if(i < na) a[i] = 0;
  if(i < nb) b[i] = 0;
}

__global__ void k_hist(const int* __restrict__ dst, int* __restrict__ cnt, int E){
  int e = blockIdx.x*256 + threadIdx.x;
  if(e < E) atomicAdd(&cnt[dst[e]], 1);
}

// ---------------- hierarchical scan: cnt[0..N) -> offs[0..N], offs[0]=0 ------

#define SCAN_TILE 2048
#define SCAN_NB ((N_NODES + SCAN_TILE - 1)/SCAN_TILE)   // 25

__global__ __launch_bounds__(256) void k_scan_part(const int* __restrict__ cnt,
                                                   int* __restrict__ bsum){
  int b = blockIdx.x, tid = threadIdx.x;
  int i0 = b*SCAN_TILE + tid*8;
  int s = 0;
  #pragma unroll
  for(int j = 0; j < 8; ++j){ int i = i0 + j; s += (i < N_NODES) ? cnt[i] : 0; }
  for(int m = 32; m; m >>= 1) s += __shfl_xor(s, m);
  __shared__ int ws[4];
  if((tid & 63) == 0) ws[tid >> 6] = s;
  __syncthreads();
  if(tid == 0) bsum[b] = ws[0] + ws[1] + ws[2] + ws[3];
}

__global__ __launch_bounds__(64) void k_scan_top(int* __restrict__ bsum, int nb){
  int tid = threadIdx.x;
  int v = (tid < nb) ? bsum[tid] : 0;
  for(int s = 1; s < 64; s <<= 1){
    int t = __shfl_up(v, s);
    if(tid >= s) v += t;
  }
  if(tid < nb) bsum[tid] = v;
}

__global__ __launch_bounds__(256) void k_scan_write(int* __restrict__ cnt,
                                                    const int* __restrict__ bsum,
                                                    int* __restrict__ offs){
  int b = blockIdx.x, tid = threadIdx.x;
  int lane = tid & 63, wv = tid >> 6;
  int i0 = b*SCAN_TILE + tid*8;
  int v[8]; int s = 0;
  #pragma unroll
  for(int j = 0; j < 8; ++j){
    int i = i0 + j;
    v[j] = (i < N_NODES) ? cnt[i] : 0;
    s += v[j];
  }
  #pragma unroll
  for(int j = 0; j < 8; ++j){ int i = i0 + j; if(i < N_NODES) cnt[i] = 0; }
  int incl = s;
  for(int sh = 1; sh < 64; sh <<= 1){
    int t = __shfl_up(incl, sh);
    if(lane >= sh) incl += t;
  }
  __shared__ int wtot[4];
  if(lane == 63) wtot[wv] = incl;
  __syncthreads();
  int woff = 0;
  for(int w = 0; w < wv; ++w) woff += wtot[w];
  int excl = woff + incl - s;
  int run = ((b > 0) ? bsum[b-1] : 0) + excl;
  #pragma unroll
  for(int j = 0; j < 8; ++j){
    int i = i0 + j;
    run += v[j];
    if(i < N_NODES) offs[i+1] = run;
  }
  if(b == 0 && tid == 0) offs[0] = 0;
}

__global__ void k_scatter(const int* __restrict__ src, const int* __restrict__ dst,
                          const int* __restrict__ offs, int* __restrict__ cur,
                          int* __restrict__ csr, int E){
  int e = blockIdx.x*256 + threadIdx.x;
  if(e < E){
    int d = dst[e];
    int p = offs[d] + atomicAdd(&cur[d], 1);
    if(p >= 0 && p < E) csr[p] = src[e];
  }
}

// ---------------- mark nodes whose h1 is actually consumed by layer 2 --------
// needed: nid nodes (er2) + their in-neighbors (el2/feat2).

__global__ __launch_bounds__(64) void k_mark(const int* __restrict__ nid,
                                             const int* __restrict__ offs,
                                             const int* __restrict__ csr,
                                             unsigned char* __restrict__ mark){
  unsigned n = (unsigned)nid[blockIdx.x];
  if(n >= N_NODES) return;
  if(threadIdx.x == 0) mark[n] = 1;
  int o0 = offs[n], o1 = offs[n+1];
  for(int j = o0 + (int)threadIdx.x; j < o1; j += 64){
    unsigned s = (unsigned)csr[j];
    if(s < N_NODES) mark[s] = 1;
  }
}

// ---------------- W transpose+convert: W f32 [128][384] -> Wt bf16 [384][128] -------

__global__ void k_wt(const float* __restrict__ W, bf16* __restrict__ Wt){
  int i = blockIdx.x*256 + threadIdx.x;
  if(i < HEADS*HDIM*HDIM){
    int n = i >> 7, k = i & 127;
    Wt[i] = __float2bfloat16(W[k*(HEADS*HDIM) + n]);
  }
}

// ---------------- GEMM + fused el/er + fp8 feat write ----------------
// block 256 thr = 4 waves (2x2); tile 64 rows x 128 cols (one full head).

template<int AF32>
__global__ __launch_bounds__(256) void k_gemm(const void* __restrict__ Av,
                                              const bf16* __restrict__ Wt,
                                              const float* __restrict__ al,
                                              const float* __restrict__ ar,
                                              fp8t* __restrict__ feat8,
                                              float* __restrict__ el4,
                                              float* __restrict__ er4, int M){
  int tid  = threadIdx.x;
  int wave = tid >> 6, lane = tid & 63;
  int wr = wave >> 1, wc = wave & 1;
  int row0 = blockIdx.x*64 + wr*32;
  int col0 = blockIdx.y*128 + wc*64;
  int l15 = lane & 15, lhi = lane >> 4;

  f32x4 acc[2][4] = {};
  for(int kk = 0; kk < 4; ++kk){
    int kb = kk*32 + lhi*8;
    v8bf a[2], b[4];
    for(int mi = 0; mi < 2; ++mi){
      int r = row0 + mi*16 + l15;
      if(r >= M) r = M - 1;                 // clamp; stores are guarded
      if constexpr(AF32){
        const float* ap = (const float*)Av + (size_t)r*HDIM + kb;
        f32x4 lo = *reinterpret_cast<const f32x4*>(ap);
        f32x4 hi = *reinterpret_cast<const f32x4*>(ap + 4);
        #pragma unroll
        for(int j = 0; j < 4; ++j){ a[mi][j] = (__bf16)lo[j]; a[mi][4+j] = (__bf16)hi[j]; }
      } else {
        a[mi] = *reinterpret_cast<const v8bf*>((const bf16*)Av + (size_t)r*HDIM + kb);
      }
    }
    for(int ni = 0; ni < 4; ++ni){
      int c = col0 + ni*16 + l15;
      b[ni] = *reinterpret_cast<const v8bf*>(Wt + (size_t)c*HDIM + kb);
    }
    for(int mi = 0; mi < 2; ++mi)
      for(int ni = 0; ni < 4; ++ni)
        acc[mi][ni] = __builtin_amdgcn_mfma_f32_16x16x32_bf16(a[mi], b[ni], acc[mi][ni], 0, 0, 0);
  }

  // ---- fused el/er reduction (f32, from accumulators) ----
  const float* alh = al + blockIdx.y*HDIM;
  const float* arh = ar + blockIdx.y*HDIM;
  float alv[4], arv[4];
  #pragma unroll
  for(int ni = 0; ni < 4; ++ni){
    int d = wc*64 + ni*16 + l15;
    alv[ni] = alh[d]; arv[ni] = arh[d];
  }
  __shared__ float red[2][64][2];          // [wc][row][el/er]
  __shared__ int4 tile4[512];              // 64 x 128 fp8 bytes
  fp8t* tile8 = (fp8t*)tile4;

  #pragma unroll
  for(int mi = 0; mi < 2; ++mi){
    #pragma unroll
    for(int j = 0; j < 4; ++j){
      float pe = 0.f, pr = 0.f;
      #pragma unroll
      for(int ni = 0; ni < 4; ++ni){
        pe += acc[mi][ni][j]*alv[ni];
        pr += acc[mi][ni][j]*arv[ni];
      }
      for(int k = 8; k; k >>= 1){ pe += __shfl_xor(pe, k); pr += __shfl_xor(pr, k); }
      int row_l = wr*32 + mi*16 + lhi*4 + j;
      if(l15 == 0){ red[wc][row_l][0] = pe; red[wc][row_l][1] = pr; }
    }
  }
  // ---- fp8 convert into LDS tile ----
  #pragma unroll
  for(int mi = 0; mi < 2; ++mi)
    #pragma unroll
    for(int j = 0; j < 4; ++j){
      int row_l = wr*32 + mi*16 + lhi*4 + j;
      #pragma unroll
      for(int ni = 0; ni < 4; ++ni){
        float x = acc[mi][ni][j];
        unsigned bb = (unsigned)__builtin_amdgcn_cvt_pk_fp8_f32(x, x, 0, false) & 0xFFu;
        tile8[row_l*128 + wc*64 + ni*16 + l15] = (fp8t)bb;
      }
    }
  __syncthreads();

  if(tid < 64){
    int r = blockIdx.x*64 + tid;
    if(r < M){
      el4[(size_t)r*4 + blockIdx.y] = red[0][tid][0] + red[1][tid][0];
      er4[(size_t)r*4 + blockIdx.y] = red[0][tid][1] + red[1][tid][1];
    }
  }
  #pragma unroll
  for(int pass = 0; pass < 2; ++pass){
    int off = pass*4096 + tid*16;
    int row_l = off >> 7, col = off & 127;
    int r = blockIdx.x*64 + row_l;
    if(r < M)
      *reinterpret_cast<int4*>(feat8 + (size_t)r*(HEADS*HDIM) + blockIdx.y*HDIM + col) =
          tile4[off >> 4];
  }
}

// ---------------- aggregation: one block (128 thr) per dst node ----------------

__device__ __forceinline__ float lrelu(float x){ return x > 0.f ? x : NEG_SLOPE*x; }
__device__ __forceinline__ float cvt8(fp8t b){
  return __builtin_amdgcn_cvt_f32_fp8((int)b, 0);
}

#define AGG_CHUNK 128

template<int USE_LIST, int OUT_F32, int USE_MARK>
__global__ __launch_bounds__(128) void k_agg(const fp8t* __restrict__ feat8,
                                             const float* __restrict__ el4,
                                             const float* __restrict__ er4,
                                             const float* __restrict__ bias,
                                             const int* __restrict__ offs,
                                             const int* __restrict__ csr,
                                             const int* __restrict__ list,
                                             const unsigned char* __restrict__ mark,
                                             void* __restrict__ hout){
  int bid = blockIdx.x;
  int n = USE_LIST ? list[bid] : bid;
  if(USE_MARK){ if(!mark[n]) return; }
  int tid = threadIdx.x, lane = tid & 63, wv = tid >> 6;
  __shared__ float s_m[2][3], s_s[2][3];
  __shared__ float s_alpha[AGG_CHUNK][4];
  __shared__ int   s_src[AGG_CHUNK];
  __shared__ float s_facc[HEADS*HDIM];
  int o0 = offs[n];
  int deg = offs[n+1] - o0;
  if(deg < 0 || deg > N_EDGES) deg = 0;
  float4 erv = *reinterpret_cast<const float4*>(er4 + (size_t)n*4);

  if(deg <= AGG_CHUNK){
    // ---------- fast path: logits once, dword-granular accumulate ----------
    float x0 = -1e30f, x1 = -1e30f, x2 = -1e30f; int s = 0;
    if(tid < deg){
      unsigned su = (unsigned)csr[o0 + tid];
      if(su >= N_NODES) su = 0;
      s = (int)su;
      float4 elv = *reinterpret_cast<const float4*>(el4 + (size_t)s*4);
      x0 = lrelu(elv.x + erv.x);
      x1 = lrelu(elv.y + erv.y);
      x2 = lrelu(elv.z + erv.z);
    }
    float m0 = x0, m1 = x1, m2 = x2;
    for(int k = 32; k; k >>= 1){
      m0 = fmaxf(m0, __shfl_xor(m0, k));
      m1 = fmaxf(m1, __shfl_xor(m1, k));
      m2 = fmaxf(m2, __shfl_xor(m2, k));
    }
    if(lane == 0){ s_m[wv][0] = m0; s_m[wv][1] = m1; s_m[wv][2] = m2; }
    __syncthreads();
    m0 = fmaxf(s_m[0][0], s_m[1][0]);
    m1 = fmaxf(s_m[0][1], s_m[1][1]);
    m2 = fmaxf(s_m[0][2], s_m[1][2]);
    float e0 = (tid < deg) ? __expf(x0 - m0) : 0.f;
    float e1 = (tid < deg) ? __expf(x1 - m1) : 0.f;
    float e2 = (tid < deg) ? __expf(x2 - m2) : 0.f;
    float t0 = e0, t1 = e1, t2 = e2;
    for(int k = 32; k; k >>= 1){
      t0 += __shfl_xor(t0, k); t1 += __shfl_xor(t1, k); t2 += __shfl_xor(t2, k);
    }
    if(lane == 0){ s_s[wv][0] = t0; s_s[wv][1] = t1; s_s[wv][2] = t2; }
    if(tid < deg){
      s_src[tid] = s;
      s_alpha[tid][0] = e0; s_alpha[tid][1] = e1; s_alpha[tid][2] = e2;
    }
    __syncthreads();
    if(tid < 96){
      int head = tid >> 5;
      float S = s_s[0][head] + s_s[1][head];
      float ih = (S > 0.f) ? 1.f/S : 0.f;
      float a0 = 0.f, a1 = 0.f, a2 = 0.f, a3 = 0.f;
      for(int i = 0; i < deg; ++i){
        unsigned u = *reinterpret_cast<const unsigned*>(
            feat8 + (size_t)s_src[i]*(HEADS*HDIM) + tid*4);
        float al = s_alpha[i][head];
        a0 += al*__builtin_amdgcn_cvt_f32_fp8((int)u, 0);
        a1 += al*__builtin_amdgcn_cvt_f32_fp8((int)u, 1);
        a2 += al*__builtin_amdgcn_cvt_f32_fp8((int)u, 2);
        a3 += al*__builtin_amdgcn_cvt_f32_fp8((int)u, 3);
      }
      float4 w; w.x = a0*ih; w.y = a1*ih; w.z = a2*ih; w.w = a3*ih;
      *reinterpret_cast<float4*>(s_facc + tid*4) = w;
    }
    __syncthreads();
    float r = (s_facc[tid] + s_facc[HDIM + tid] + s_facc[2*HDIM + tid]
             + bias[tid] + bias[HDIM + tid] + bias[2*HDIM + tid])*(1.f/3.f);
    if(OUT_F32) ((float*)hout)[(size_t)bid*HDIM + tid] = r;
    else        ((bf16*)hout)[(size_t)bid*HDIM + tid] = __float2bfloat16(r);
    return;
  }

  // ---------- general path (deg > 128): chunked online softmax ----------
  float M0 = -1e30f, M1 = -1e30f, M2 = -1e30f;
  float S0 = 0.f, S1 = 0.f, S2 = 0.f;
  for(int base = 0; base < deg; base += AGG_CHUNK){
    int cn = min(AGG_CHUNK, deg - base);
    float x0 = -1e30f, x1 = -1e30f, x2 = -1e30f;
    if(tid < cn){
      unsigned su = (unsigned)csr[o0 + base + tid];
      if(su >= N_NODES) su = 0;
      float4 elv = *reinterpret_cast<const float4*>(el4 + (size_t)su*4);
      x0 = lrelu(elv.x + erv.x);
      x1 = lrelu(elv.y + erv.y);
      x2 = lrelu(elv.z + erv.z);
    }
    float m0 = x0, m1 = x1, m2 = x2;
    for(int k = 32; k; k >>= 1){
      m0 = fmaxf(m0, __shfl_xor(m0, k));
      m1 = fmaxf(m1, __shfl_xor(m1, k));
      m2 = fmaxf(m2, __shfl_xor(m2, k));
    }
    if(lane == 0){ s_m[wv][0] = m0; s_m[wv][1] = m1; s_m[wv][2] = m2; }
    __syncthreads();
    float nm0 = fmaxf(M0, fmaxf(s_m[0][0], s_m[1][0]));
    float nm1 = fmaxf(M1, fmaxf(s_m[0][1], s_m[1][1]));
    float nm2 = fmaxf(M2, fmaxf(s_m[0][2], s_m[1][2]));
    float e0 = (tid < cn) ? __expf(x0 - nm0) : 0.f;
    float e1 = (tid < cn) ? __expf(x1 - nm1) : 0.f;
    float e2 = (tid < cn) ? __expf(x2 - nm2) : 0.f;
    float t0 = e0, t1 = e1, t2 = e2;
    for(int k = 32; k; k >>= 1){
      t0 += __shfl_xor(t0, k); t1 += __shfl_xor(t1, k); t2 += __shfl_xor(t2, k);
    }
    if(lane == 0){ s_s[wv][0] = t0; s_s[wv][1] = t1; s_s[wv][2] = t2; }
    __syncthreads();
    S0 = S0*__expf(M0 - nm0) + s_s[0][0] + s_s[1][0];
    S1 = S1*__expf(M1 - nm1) + s_s[0][1] + s_s[1][1];
    S2 = S2*__expf(M2 - nm2) + s_s[0][2] + s_s[1][2];
    M0 = nm0; M1 = nm1; M2 = nm2;
  }
  float i0 = 1.f/S0, i1 = 1.f/S1, i2 = 1.f/S2;

  float a0 = 0.f, a1 = 0.f, a2 = 0.f;
  for(int base = 0; base < deg; base += AGG_CHUNK){
    int cn = min(AGG_CHUNK, deg - base);
    __syncthreads();
    if(tid < cn){
      unsigned su = (unsigned)csr[o0 + base + tid];
      if(su >= N_NODES) su = 0;
      float4 elv = *reinterpret_cast<const float4*>(el4 + (size_t)su*4);
      s_src[tid] = (int)su;
      s_alpha[tid][0] = __expf(lrelu(elv.x + erv.x) - M0)*i0;
      s_alpha[tid][1] = __expf(lrelu(elv.y + erv.y) - M1)*i1;
      s_alpha[tid][2] = __expf(lrelu(elv.z + erv.z) - M2)*i2;
    }
    __syncthreads();
    for(int i = 0; i < cn; ++i){
      const fp8t* fr = feat8 + (size_t)s_src[i]*(HEADS*HDIM);
      a0 += s_alpha[i][0]*cvt8(fr[tid]);
      a1 += s_alpha[i][1]*cvt8(fr[HDIM + tid]);
      a2 += s_alpha[i][2]*cvt8(fr[2*HDIM + tid]);
    }
  }
  float r = (a0 + a1 + a2 + bias[tid] + bias[HDIM+tid] + bias[2*HDIM+tid])*(1.f/3.f);
  if(OUT_F32) ((float*)hout)[(size_t)bid*HDIM + tid] = r;
  else        ((bf16*)hout)[(size_t)bid*HDIM + tid] = __float2bfloat16(r);
}

// ---------------- final assembly (f32 output) ----------------

#define SEQ_SZ   (BB*LL*4*HDIM)
#define SEQR_OFF SEQ_SZ
#define SEQR_SZ  (BB*LL*3*HDIM)
#define SH_OFF   (SEQ_SZ + SEQR_SZ)

__global__ __launch_bounds__(128) void k_assemble(const float* __restrict__ h2s,
                                                  const float* __restrict__ ent_e,
                                                  const float* __restrict__ rel_e,
                                                  const float* __restrict__ glob,
                                                  const float* __restrict__ sht,
                                                  const int* __restrict__ s_tem,
                                                  const int* __restrict__ r_tem,
                                                  float* __restrict__ out){
  int p = blockIdx.x;
  int d = threadIdx.x;
  int b = p / LL;
  float emb = h2s[(size_t)p*HDIM + d];
  float ent = ent_e[(size_t)s_tem[b]*HDIM + d];
  float rel = rel_e[(size_t)r_tem[b]*HDIM + d];
  float gl  = glob[(size_t)p*HDIM + d];
  size_t so = (size_t)p*(4*HDIM);
  out[so + d] = emb; out[so + HDIM + d] = ent;
  out[so + 2*HDIM + d] = rel; out[so + 3*HDIM + d] = gl;
  size_t ro = SEQR_OFF + (size_t)p*(3*HDIM);
  out[ro + d] = emb; out[ro + HDIM + d] = ent; out[ro + 2*HDIM + d] = gl;
  if(d == 0) out[SH_OFF + p] = sht[p];
}

// ---------------- launch ----------------

extern "C" void kernel_launch(void* const* d_in, const int* in_sizes, int n_in,
                              void* d_out, int out_size, void* d_ws, size_t ws_size,
                              hipStream_t stream){
  const float* node_feat = (const float*)d_in[0];
  const float* W1        = (const float*)d_in[1];
  const float* attn_l1   = (const float*)d_in[2];
  const float* attn_r1   = (const float*)d_in[3];
  const float* b1        = (const float*)d_in[4];
  const float* W2        = (const float*)d_in[5];
  const float* attn_l2   = (const float*)d_in[6];
  const float* attn_r2   = (const float*)d_in[7];
  const float* b2        = (const float*)d_in[8];
  const float* ent_emb   = (const float*)d_in[9];
  const float* rel_emb   = (const float*)d_in[10];
  const float* glob      = (const float*)d_in[11];
  const float* sht       = (const float*)d_in[12];
  const int*  e_src      = (const int*)d_in[13];
  const int*  e_dst      = (const int*)d_in[14];
  const int*  nid        = (const int*)d_in[15];
  const int*  s_tem      = (const int*)d_in[16];
  const int*  r_tem      = (const int*)d_in[17];
  float* out = (float*)d_out;

  char* ws = (char*)d_ws;
  size_t cur_off = 0;
  auto alloc = [&](size_t bytes)->char*{
    char* r = ws + cur_off;
    cur_off += (bytes + 255) & ~(size_t)255;
    return r;
  };
  fp8t*  feat8 = (fp8t*) alloc((size_t)N_NODES*HEADS*HDIM);      // 19.2 MB
  bf16*  h1    = (bf16*) alloc((size_t)N_NODES*HDIM*2);          // 12.8 MB
  float* h2s   = (float*)alloc((size_t)BB*LL*HDIM*4);            // 2.6 MB
  float* el4   = (float*)alloc((size_t)N_NODES*4*4);             // 0.8 MB
  float* er4   = (float*)alloc((size_t)N_NODES*4*4);             // 0.8 MB
  bf16*  wt1   = (bf16*) alloc((size_t)HEADS*HDIM*HDIM*2);
  bf16*  wt2   = (bf16*) alloc((size_t)HEADS*HDIM*HDIM*2);
  int*   offs  = (int*)  alloc((size_t)(N_NODES+1)*4);
  int*   cnt   = (int*)  alloc((size_t)N_NODES*4);               // also cursor
  int*   bsum  = (int*)  alloc((size_t)SCAN_NB*4);
  unsigned char* mark = (unsigned char*)alloc((size_t)N_NODES);
  int*   csr   = (int*)  alloc((size_t)N_EDGES*4);

  // CSR build (shared by both layers); zero cnt + mark in one launch
  k_zero2<<<(N_NODES+255)/256, 256, 0, stream>>>(cnt, N_NODES,
                                                 (int*)mark, (N_NODES+3)/4);
  k_hist<<<(N_EDGES+255)/256, 256, 0, stream>>>(e_dst, cnt, N_EDGES);
  k_scan_part<<<SCAN_NB, 256, 0, stream>>>(cnt, bsum);
  k_scan_top<<<1, 64, 0, stream>>>(bsum, SCAN_NB);
  k_scan_write<<<SCAN_NB, 256, 0, stream>>>(cnt, bsum, offs);   // also zeroes cnt
  k_scatter<<<(N_EDGES+255)/256, 256, 0, stream>>>(e_src, e_dst, offs, cnt, csr, N_EDGES);
  k_mark<<<BB*LL, 64, 0, stream>>>(nid, offs, csr, mark);

  // weight transposes
  k_wt<<<(HEADS*HDIM*HDIM+255)/256, 256, 0, stream>>>(W1, wt1);
  k_wt<<<(HEADS*HDIM*HDIM+255)/256, 256, 0, stream>>>(W2, wt2);

  dim3 ggrid((N_NODES + 63)/64, HEADS);

  // Layer 1 (agg only for nodes layer 2 consumes)
  k_gemm<1><<<ggrid, 256, 0, stream>>>((const void*)node_feat, wt1, attn_l1, attn_r1,
                                       feat8, el4, er4, N_NODES);
  k_agg<0,0,1><<<N_NODES, 128, 0, stream>>>(feat8, el4, er4, b1, offs, csr,
                                            nullptr, mark, (void*)h1);

  // Layer 2 (agg only over the nodes assemble needs)
  k_gemm<0><<<ggrid, 256, 0, stream>>>((const void*)h1, wt2, attn_l2, attn_r2,
                                       feat8, el4, er4, N_NODES);
  k_agg<1,1,0><<<BB*LL, 128, 0, stream>>>(feat8, el4, er4, b2, offs, csr,
                                          nid, nullptr, (void*)h2s);

  // Assembly (f32 output)
  k_assemble<<<BB*LL, 128, 0, stream>>>(h2s, ent_emb, rel_emb, glob, sht,
                                        s_tem, r_tem, out);
}